// Round 8
// baseline (891.283 us; speedup 1.0000x reference)
//
#include <hip/hip_runtime.h>
#include <hip/hip_bf16.h>
#include <math.h>

// ---------------- problem constants ----------------
#define BB 32
#define NN 512
#define BN 16384          // BB*NN
#define DD 1024
#define HID 512
#define G4 2048           // 4*HID
#define HLEN 15
#define IND 4
#define EPS 1e-5f

typedef __bf16 v8bf __attribute__((ext_vector_type(8)));
typedef float  v4f  __attribute__((ext_vector_type(4)));

__device__ __forceinline__ void async_copy16(const __bf16* gsrc, __bf16* ldst) {
    __builtin_amdgcn_global_load_lds(
        (const __attribute__((address_space(1))) void*)gsrc,
        (__attribute__((address_space(3))) void*)ldst, 16, 0, 0);
}

#define VMCNTI(n) asm volatile("s_waitcnt vmcnt(" #n ")" ::: "memory")
#define VMCNT0 VMCNTI(0)
#define LGKM0  asm volatile("s_waitcnt lgkmcnt(0)" ::: "memory")
#define MEMFENCE asm volatile("" ::: "memory")

// fast transcendentals: v_exp_f32 + v_rcp_f32 (rel err ~1e-6, fine vs 0.11 threshold)
#define LOG2E 1.44269504f
__device__ __forceinline__ float sigmf(float x) {
    return __builtin_amdgcn_rcpf(1.0f + __builtin_amdgcn_exp2f(-LOG2E * x));
}
__device__ __forceinline__ float tanh_fast(float x) {
    return 1.0f - 2.0f * __builtin_amdgcn_rcpf(1.0f + __builtin_amdgcn_exp2f(2.0f * LOG2E * x));
}

// ---------------- weight prep ----------------
// whh_b: NATIVE layout bf16 2048x512 (gate blocks i,f,g,o of 512 rows each);
// wrel_b: bf16 1024x512; wih_i: unit-interleaved fp32 2048x4; bsum: b_ih+b_hh interleaved.
__global__ void convert_w(const float* __restrict__ Whh, const float* __restrict__ Wrel,
                          const float* __restrict__ Wih, const float* __restrict__ bih,
                          const float* __restrict__ bhh,
                          __bf16* __restrict__ whh_b, __bf16* __restrict__ wrel_b,
                          float* __restrict__ wih_i, float* __restrict__ bsum) {
    int i = blockIdx.x * 256 + threadIdx.x;
    if (i < G4 * HID) whh_b[i] = (__bf16)Whh[i];
    if (i < DD * HID) wrel_b[i] = (__bf16)Wrel[i];
    if (i < G4) {
        int uu = i >> 2, gi = i & 3;
        int src = gi * HID + uu;
        wih_i[i * 4 + 0] = Wih[src * 4 + 0];
        wih_i[i * 4 + 1] = Wih[src * 4 + 1];
        wih_i[i * 4 + 2] = Wih[src * 4 + 2];
        wih_i[i * 4 + 3] = Wih[src * 4 + 3];
        bsum[i] = bih[src] + bhh[src];
    }
}

// ---------------- per-batch gate alpha ----------------
__global__ void alpha_kernel(const float* __restrict__ es, const float* __restrict__ gc,
                             const float* __restrict__ W_g1, const float* __restrict__ b_g1,
                             const float* __restrict__ W_g2, const float* __restrict__ b_g2,
                             float* __restrict__ alpha) {
    int b = threadIdx.x;
    if (b >= BB) return;
    float c0 = es[b], c1 = gc[b];
    float acc = b_g2[0];
    for (int k = 0; k < 16; ++k) {
        float hk = c0 * W_g1[k * 2] + c1 * W_g1[k * 2 + 1] + b_g1[k];
        hk = fmaxf(hk, 0.0f);
        acc += hk * W_g2[k];
    }
    alpha[b] = 1.0f / (1.0f + expf(-acc));
}

// ---------------- t=0 cell (h0 = c0 = 0 -> gates from input only) ----------------
__global__ __launch_bounds__(256) void lstm_cell0(const float* __restrict__ traj,
                                                  const float* __restrict__ wih_i,
                                                  const float* __restrict__ bsum,
                                                  float* __restrict__ c,
                                                  __bf16* __restrict__ h) {
    int idx = blockIdx.x * 256 + threadIdx.x;   // row*512 + u
    int row = idx >> 9;
    float4 x = *(const float4*)(traj + (size_t)row * (HLEN * IND));   // t = 0, 16B aligned
    int u = idx & 511;
    float g[4];
    #pragma unroll
    for (int gi = 0; gi < 4; ++gi) {
        int j = u * 4 + gi;
        float4 w = *(const float4*)(wih_i + (size_t)j * 4);
        g[gi] = bsum[j] + w.x * x.x + w.y * x.y + w.z * x.z + w.w * x.w;
    }
    float ig = sigmf(g[0]);
    float gg = tanh_fast(g[2]);
    float og = sigmf(g[3]);
    float cn = ig * gg;                    // f*c0 = 0
    c[idx] = cn;
    h[idx] = (__bf16)(og * tanh_fast(cn));
}

// ================= 128x256 BK=32 GEMM core, 2 blocks/CU =================
// Tile: 128 rows x 256 cols (lstm: 64 units x 4 gates). 8 waves (2M x 4N):
// wave = 64 rows x 64 cols; acc = 16 cells/lane (64 f32 regs). LDS 48 KiB:
// 2 dbuf x [A 8KB (128x32) | B 16KB (256x32)]. __launch_bounds__(512,4)
// forces <=128 unified regs -> 16 waves/CU = 2 co-resident blocks: one
// block's epilogue/stalls overlap the other's MFMA (the r7 kernel's acc[8][4]
// = 252 unified regs capped it at 1 block/CU -- the real occupancy binder).
// Per K-tile (single phase): STAGE(kt+1, 3 glds) -> vmcnt(3) (kt landed,
// kt+1 in flight; never 0 mid-loop) -> barrier -> 8 ds_read_b128 -> lgkm0 +
// sched_barrier(0) (rule 18) -> setprio(1) 16 MFMA setprio(0) -> barrier
// (all reads done before kt+1's overwrite of this buffer at kt+2).
// SWIZZLE (64B rows, 4 slots): bank = (row*16 + slot*4 + w) mod 32; within a
// 16-lane read group rows alternate parity (+16 banks) and (row>>1)&3 cycles
// 0..3 -> physical slot l = p ^ ((r>>1)&3) gives 2 lanes/bank = free. Write
// side: glds dest LINEAR, global source chunk pre-swizzled (both-sides rule).
// Read: pcs = ((lane>>4) ^ ((mrow>>1)&3))*8.

__global__ __launch_bounds__(512, 4) void gemm_lstm(const __bf16* __restrict__ A,
                                                    const __bf16* __restrict__ Bm,
                                                    const float* __restrict__ traj,
                                                    const float* __restrict__ wih_i,
                                                    const float* __restrict__ bsum,
                                                    float* __restrict__ c,
                                                    __bf16* __restrict__ h_out,
                                                    int t) {
    __shared__ __bf16 sm[2][12288];   // 48 KiB: [buf][A 4096 | B 8192] elems

    const int tid    = threadIdx.x;
    const int lane   = tid & 63;
    const int wave   = tid >> 6;      // 0..7
    const int wave_m = wave & 1;      // row half (64 rows)
    const int wn     = wave >> 1;     // 0..3: 16-unit sub-block
    const int bm     = blockIdx.x;    // rows [bm*128, +128)
    const int ub     = blockIdx.y;    // units [ub*64, +64)
    const int u0     = ub * 64;

    const int mrow = lane & 15;
    const int pcs  = (((lane >> 4) ^ ((mrow >> 1) & 3)) << 3);

    // staging sources, pre-swizzled. A: 512 chunks (ca=tid): r=ca>>2, p=ca&3.
    // B: 1024 chunks (ca=tid, tid+512): r=ca>>2 -> gate g=r>>6, ul=r&63.
    const int rA = tid >> 2;
    const int lA_ = (tid & 3) ^ ((rA >> 1) & 3);
    const __bf16* pa = A + (size_t)(bm * 128 + rA) * HID + lA_ * 8;
    const __bf16* pb[2];
    #pragma unroll
    for (int s = 0; s < 2; ++s) {
        const int ca = tid + s * 512;
        const int r  = ca >> 2;
        const int l  = (ca & 3) ^ ((r >> 1) & 3);
        pb[s] = Bm + (size_t)((r >> 6) * HID + u0 + (r & 63)) * HID + l * 8;
    }
    const int wb = wave * 512;        // wave-uniform LDS elem base

    #define STAGE(buf, kt) do {                                      \
        async_copy16(pa    + (kt) * 32, &sm[buf][wb]);               \
        async_copy16(pb[0] + (kt) * 32, &sm[buf][4096 + wb]);        \
        async_copy16(pb[1] + (kt) * 32, &sm[buf][8192 + wb]); } while (0)

    v4f acc[4][4] = {};   // [ii row-frag][gate]

    STAGE(0, 0);
    #pragma unroll
    for (int kt = 0; kt < 16; ++kt) {
        const int cb = kt & 1;
        if (kt < 15) { STAGE(cb ^ 1, kt + 1); VMCNTI(3); } else { VMCNT0; }
        __builtin_amdgcn_s_barrier();
        MEMFENCE;
        const __bf16* smb = &sm[cb][0];
        v8bf ar[4], br[4];
        #pragma unroll
        for (int ii = 0; ii < 4; ++ii)
            ar[ii] = *(const v8bf*)(smb + (wave_m * 64 + ii * 16 + mrow) * 32 + pcs);
        #pragma unroll
        for (int j = 0; j < 4; ++j)
            br[j] = *(const v8bf*)(smb + 4096 + (j * 64 + wn * 16 + mrow) * 32 + pcs);
        LGKM0;
        __builtin_amdgcn_sched_barrier(0);
        __builtin_amdgcn_s_setprio(1);
        #pragma unroll
        for (int ii = 0; ii < 4; ++ii)
            #pragma unroll
            for (int j = 0; j < 4; ++j)
                acc[ii][j] = __builtin_amdgcn_mfma_f32_16x16x32_bf16(ar[ii], br[j], acc[ii][j], 0, 0, 0);
        __builtin_amdgcn_s_setprio(0);
        __builtin_amdgcn_s_barrier();
        MEMFENCE;
    }
    #undef STAGE

    // ---- register-only cell update: lane owns unit u_glob; 4x4 cells ----
    const int u_glob = u0 + wn * 16 + mrow;
    const int crow4  = (lane >> 4) * 4;
    float wv[4][4], bs4[4];
    #pragma unroll
    for (int gi = 0; gi < 4; ++gi) {
        float4 wp = *(const float4*)(wih_i + (size_t)(u_glob * 4 + gi) * 4);
        wv[gi][0] = wp.x; wv[gi][1] = wp.y; wv[gi][2] = wp.z; wv[gi][3] = wp.w;
        bs4[gi] = bsum[u_glob * 4 + gi];
    }
    #pragma unroll
    for (int ii = 0; ii < 4; ++ii) {
        const int growb = bm * 128 + wave_m * 64 + ii * 16 + crow4;
        #pragma unroll
        for (int r = 0; r < 4; ++r) {
            const int grow = growb + r;
            const float4 x = *(const float4*)(traj + (size_t)grow * (HLEN * IND) + t * IND);
            float g[4];
            #pragma unroll
            for (int gi = 0; gi < 4; ++gi)
                g[gi] = acc[ii][gi][r] + bs4[gi]
                      + wv[gi][0] * x.x + wv[gi][1] * x.y + wv[gi][2] * x.z + wv[gi][3] * x.w;
            float ig = sigmf(g[0]);
            float fg = sigmf(g[1]);
            float gg = tanh_fast(g[2]);
            float og = sigmf(g[3]);
            size_t ci = (size_t)grow * HID + u_glob;
            float cn = fg * c[ci] + ig * gg;
            c[ci] = cn;
            h_out[ci] = (__bf16)(og * tanh_fast(cn));
        }
    }
}

// ---------------- projection GEMM (128x256 BK=32): hrel = h @ W_rel^T ----------------
__global__ __launch_bounds__(512, 4) void gemm_proj(const __bf16* __restrict__ A,
                                                    const __bf16* __restrict__ Bm,
                                                    __bf16* __restrict__ Cout) {
    __shared__ __bf16 sm[2][12288];

    const int tid    = threadIdx.x;
    const int lane   = tid & 63;
    const int wave   = tid >> 6;
    const int wave_m = wave & 1;
    const int wn     = wave >> 1;
    const int bm     = blockIdx.x;    // rows [bm*128, +128)
    const int bn     = blockIdx.y;    // cols [bn*256, +256)

    const int mrow = lane & 15;
    const int pcs  = (((lane >> 4) ^ ((mrow >> 1) & 3)) << 3);

    const int rA = tid >> 2;
    const int lA_ = (tid & 3) ^ ((rA >> 1) & 3);
    const __bf16* pa = A + (size_t)(bm * 128 + rA) * HID + lA_ * 8;
    const __bf16* pb[2];
    #pragma unroll
    for (int s = 0; s < 2; ++s) {
        const int ca = tid + s * 512;
        const int r  = ca >> 2;
        const int l  = (ca & 3) ^ ((r >> 1) & 3);
        pb[s] = Bm + (size_t)(bn * 256 + r) * HID + l * 8;
    }
    const int wb = wave * 512;

    #define STAGE(buf, kt) do {                                      \
        async_copy16(pa    + (kt) * 32, &sm[buf][wb]);               \
        async_copy16(pb[0] + (kt) * 32, &sm[buf][4096 + wb]);        \
        async_copy16(pb[1] + (kt) * 32, &sm[buf][8192 + wb]); } while (0)

    v4f acc[4][4] = {};

    STAGE(0, 0);
    #pragma unroll
    for (int kt = 0; kt < 16; ++kt) {
        const int cb = kt & 1;
        if (kt < 15) { STAGE(cb ^ 1, kt + 1); VMCNTI(3); } else { VMCNT0; }
        __builtin_amdgcn_s_barrier();
        MEMFENCE;
        const __bf16* smb = &sm[cb][0];
        v8bf ar[4], br[4];
        #pragma unroll
        for (int ii = 0; ii < 4; ++ii)
            ar[ii] = *(const v8bf*)(smb + (wave_m * 64 + ii * 16 + mrow) * 32 + pcs);
        #pragma unroll
        for (int j = 0; j < 4; ++j)
            br[j] = *(const v8bf*)(smb + 4096 + (j * 64 + wn * 16 + mrow) * 32 + pcs);
        LGKM0;
        __builtin_amdgcn_sched_barrier(0);
        __builtin_amdgcn_s_setprio(1);
        #pragma unroll
        for (int ii = 0; ii < 4; ++ii)
            #pragma unroll
            for (int j = 0; j < 4; ++j)
                acc[ii][j] = __builtin_amdgcn_mfma_f32_16x16x32_bf16(ar[ii], br[j], acc[ii][j], 0, 0, 0);
        __builtin_amdgcn_s_setprio(0);
        __builtin_amdgcn_s_barrier();
        MEMFENCE;
    }
    #undef STAGE

    const int crow4 = (lane >> 4) * 4;
    #pragma unroll
    for (int ii = 0; ii < 4; ++ii) {
        const int growb = bm * 128 + wave_m * 64 + ii * 16 + crow4;
        #pragma unroll
        for (int j = 0; j < 4; ++j) {
            const int gcol = bn * 256 + j * 64 + wn * 16 + mrow;
            #pragma unroll
            for (int r = 0; r < 4; ++r)
                Cout[(size_t)(growb + r) * DD + gcol] = (__bf16)acc[ii][j][r];
        }
    }
}

// ---------------- fused gate-mix + residual + LayerNorm ----------------
__global__ __launch_bounds__(256) void fuse_ln(const float* __restrict__ tokens,
                                               const __bf16* __restrict__ hrel,
                                               const float* __restrict__ habs_in,
                                               const float* __restrict__ W_abs,
                                               const float* __restrict__ alpha,
                                               const float* __restrict__ gamma,
                                               const float* __restrict__ beta,
                                               float* __restrict__ out) {
    const int row = blockIdx.x;
    const int b   = row >> 9;
    const float al = alpha[b];
    const float a0 = habs_in[(size_t)row * 2];
    const float a1 = habs_in[(size_t)row * 2 + 1];
    const int tid  = threadIdx.x;
    const int lane = tid & 63;
    const int wave = tid >> 6;

    __shared__ float red[4];

    float x[4];
    float s = 0.0f;
    #pragma unroll
    for (int q = 0; q < 4; ++q) {
        int dcol = tid + q * 256;
        float habs = a0 * W_abs[dcol * 2] + a1 * W_abs[dcol * 2 + 1];
        float v = tokens[(size_t)row * DD + dcol]
                + al * (float)hrel[(size_t)row * DD + dcol]
                + (1.0f - al) * habs;
        x[q] = v;
        s += v;
    }
    #pragma unroll
    for (int off = 32; off > 0; off >>= 1) s += __shfl_down(s, off);
    if (lane == 0) red[wave] = s;
    __syncthreads();
    float mu = (red[0] + red[1] + red[2] + red[3]) * (1.0f / DD);

    float vs = 0.0f;
    #pragma unroll
    for (int q = 0; q < 4; ++q) {
        float d = x[q] - mu;
        vs += d * d;
    }
    #pragma unroll
    for (int off = 32; off > 0; off >>= 1) vs += __shfl_down(vs, off);
    __syncthreads();
    if (lane == 0) red[wave] = vs;
    __syncthreads();
    float var = (red[0] + red[1] + red[2] + red[3]) * (1.0f / DD);
    float rstd = rsqrtf(var + EPS);

    #pragma unroll
    for (int q = 0; q < 4; ++q) {
        int dcol = tid + q * 256;
        out[(size_t)row * DD + dcol] = (x[q] - mu) * rstd * gamma[dcol] + beta[dcol];
    }
}

// ---------------- host launch ----------------
extern "C" void kernel_launch(void* const* d_in, const int* in_sizes, int n_in,
                              void* d_out, int out_size, void* d_ws, size_t ws_size,
                              hipStream_t stream) {
    const float* tokens   = (const float*)d_in[0];
    const float* traj     = (const float*)d_in[1];
    const float* habs     = (const float*)d_in[2];
    const float* espeed   = (const float*)d_in[3];
    const float* gconf    = (const float*)d_in[4];
    const float* W_ih     = (const float*)d_in[5];
    const float* W_hh     = (const float*)d_in[6];
    const float* b_ih     = (const float*)d_in[7];
    const float* b_hh     = (const float*)d_in[8];
    const float* W_rel    = (const float*)d_in[9];
    const float* W_abs    = (const float*)d_in[10];
    const float* W_g1     = (const float*)d_in[11];
    const float* b_g1     = (const float*)d_in[12];
    const float* W_g2     = (const float*)d_in[13];
    const float* b_g2     = (const float*)d_in[14];
    const float* gamma    = (const float*)d_in[15];
    const float* beta     = (const float*)d_in[16];
    float* out = (float*)d_out;

    char* ws = (char*)d_ws;
    size_t off = 0;
    __bf16* whh_b  = (__bf16*)(ws + off); off += (size_t)G4 * HID * 2;     // 2 MB
    __bf16* wrel_b = (__bf16*)(ws + off); off += (size_t)DD * HID * 2;     // 1 MB
    float*  wih_i  = (float*)(ws + off);  off += (size_t)G4 * 4 * 4;       // 32 KB
    float*  bsum   = (float*)(ws + off);  off += (size_t)G4 * 4;           // 8 KB
    __bf16* h0     = (__bf16*)(ws + off); off += (size_t)BN * HID * 2;     // 16 MB
    __bf16* h1     = (__bf16*)(ws + off); off += (size_t)BN * HID * 2;     // 16 MB
    float*  c      = (float*)(ws + off);  off += (size_t)BN * HID * 4;     // 32 MB
    __bf16* hrel   = (__bf16*)(ws + off); off += (size_t)BN * DD * 2;      // 32 MB
    float*  alpha  = (float*)(ws + off);  off += 256;

    convert_w<<<(G4 * HID + 255) / 256, 256, 0, stream>>>(W_hh, W_rel, W_ih, b_ih, b_hh,
                                                          whh_b, wrel_b, wih_i, bsum);
    alpha_kernel<<<1, 64, 0, stream>>>(espeed, gconf, W_g1, b_g1, W_g2, b_g2, alpha);
    lstm_cell0<<<(BN * HID) / 256, 256, 0, stream>>>(traj, wih_i, bsum, c, h0);

    __bf16* hbuf[2] = {h0, h1};
    for (int t = 1; t < HLEN; ++t) {
        const __bf16* hin = hbuf[(t + 1) & 1];
        __bf16* hout = hbuf[t & 1];
        gemm_lstm<<<dim3(BN / 128, HID / 64), 512, 0, stream>>>(hin, whh_b, traj, wih_i, bsum,
                                                                c, hout, t);
    }
    // final h after t=14 is in hbuf[14&1] = h0
    gemm_proj<<<dim3(BN / 128, DD / 256), 512, 0, stream>>>(h0, wrel_b, hrel);
    fuse_ln<<<BN, 256, 0, stream>>>(tokens, hrel, habs, W_abs, alpha, gamma, beta, out);
}